// Round 15
// baseline (69.723 us; speedup 1.0000x reference)
//
#include <hip/hip_runtime.h>

#define B_ 32
#define T_ 8192
#define D_ 128
#define MBLK 128
#define NCHUNK 64    // T_/MBLK
#define CPB 2        // chunks per block

typedef __attribute__((ext_vector_type(8))) _Float16 half8;
typedef __attribute__((ext_vector_type(4))) _Float16 half4;
typedef __attribute__((ext_vector_type(4))) float floatx4;

__device__ __forceinline__ float tanh_fast(float x) {
    float e = __expf(2.0f * x);
    return 1.0f - __fdividef(2.0f, e + 1.0f);
}

// K0 (fused prep): blocks 0-7 pack W1 MFMA B-fragments; blocks 8-23 compute bias.
// B[k][n]: lane l holds n = ni*16 + (l&15), k = kk*32 + (l>>4)*8 + j  (j=0..7).
__global__ void prep_kernel(const float* __restrict__ W1, half8* __restrict__ W1frag,
                            const float* __restrict__ dec, const float* __restrict__ W2,
                            float* __restrict__ bias) {
    int bid = blockIdx.x, tid = threadIdx.x;
    if (bid < 8) {
        int tg = bid * 256 + tid;   // (kk*8+ni)*64+lane
        int kk = tg >> 9, ni = (tg >> 6) & 7, lane = tg & 63;
        half8 h;
        #pragma unroll
        for (int j = 0; j < 8; ++j) {
            int k = kk * 32 + ((lane >> 4) * 8) + j;
            int n = ni * 16 + (lane & 15);
            h[j] = (_Float16)W1[k * 128 + n];
        }
        W1frag[tg] = h;
    } else {
        int b = (bid - 8) * 2 + (tid >> 7);
        int d = tid & 127;
        float acc = 0.f;
        for (int h = 0; h < 128; ++h)
            acc += dec[b * 128 + h] * W2[h * 128 + d];
        bias[b * 128 + d] = acc;
    }
}

// K2 (r14 body + CPB=2 chunk loop with register prefetch):
// 512 threads = 8 waves; wave w owns rows [w*16, w*16+16) of each 128-row chunk.
// bfr persistent (staged once); chunk-1 enc loads fly under chunk-0 compute.
// Registers cap residency at 2 blocks/CU (acc 32 AGPR + ~110 VGPR, 65-128
// bucket -> 4 waves/SIMD), so 70.6 KB LDS costs nothing.
__global__ __launch_bounds__(512, 4)
void main_kernel(const float* __restrict__ enc, const half8* __restrict__ W1frag,
                 const float* __restrict__ bias, const float* __restrict__ V,
                 float* __restrict__ out_w, float* __restrict__ s_part,
                 float* __restrict__ c_part)
{
    __shared__ __align__(16) half8 bfr[2048];       // 32 KB W1 fragments (persistent)
    __shared__ __align__(16) char encl[32768];      // [128][128] f16, XOR-swizzled
    __shared__ __align__(16) float red[MBLK];       // raw logits
    __shared__ __align__(16) float ews[MBLK];       // exp(logit) weights
    __shared__ __align__(16) float c_red[8][128];   // 4 KB context partials
    __shared__ float sp[2];                         // per-wave exp sums

    const int tid = threadIdx.x;
    const int l = tid & 63;
    const int w = tid >> 6;
    const int g = l >> 4;            // k-group / col-group
    const int bid = blockIdx.x;
    const int b = bid >> 5;          // 32 blocks per batch
    const int cbase = (bid & 31) * CPB;
    const int arow = w * 16 + (l & 15);
    const float* rowp = enc + ((long)b * T_ + (long)cbase * MBLK + arow) * D_ + g * 8;

    // stage W1 fragments ONCE via async global->LDS (16B/lane)
    #pragma unroll
    for (int qi = 0; qi < 4; ++qi)
        __builtin_amdgcn_global_load_lds(
            (const __attribute__((address_space(1))) void*)(W1frag + qi * 512 + tid),
            (__attribute__((address_space(3))) void*)(bfr + qi * 512 + (w << 6)),
            16, 0, 0);

    // bias / V (L2-hot), loaded once before the single vmem drain
    float bs[8], vv[8];
    #pragma unroll
    for (int ni = 0; ni < 8; ++ni) {
        int n = ni * 16 + (l & 15);
        bs[ni] = bias[b * 128 + n];
        vv[ni] = V[n];
    }

    // enc chunk 0: lane l -> row arow, k = kk*32 + g*8 + j (8 x float4)
    float4 f0[4], f1[4];
    #pragma unroll
    for (int kk = 0; kk < 4; ++kk) {
        f0[kk] = *(const float4*)(rowp + kk * 32);
        f1[kk] = *(const float4*)(rowp + kk * 32 + 4);
    }
    __syncthreads();   // A: bfr ready (single full vmem drain per block)

    #pragma unroll 1
    for (int ci = 0; ci < CPB; ++ci) {
        const int chunk = cbase + ci;

        // convert prefetched f32 -> f16 A-fragments
        half8 afr[4];
        #pragma unroll
        for (int kk = 0; kk < 4; ++kk) {
            half8 a;
            a[0] = (_Float16)f0[kk].x; a[1] = (_Float16)f0[kk].y;
            a[2] = (_Float16)f0[kk].z; a[3] = (_Float16)f0[kk].w;
            a[4] = (_Float16)f1[kk].x; a[5] = (_Float16)f1[kk].y;
            a[6] = (_Float16)f1[kk].z; a[7] = (_Float16)f1[kk].w;
            afr[kk] = a;
        }

        // issue next chunk's enc loads — hidden under MFMA+epilogue+context
        if (ci < CPB - 1) {
            rowp += MBLK * D_;
            #pragma unroll
            for (int kk = 0; kk < 4; ++kk) {
                f0[kk] = *(const float4*)(rowp + kk * 32);
                f1[kk] = *(const float4*)(rowp + kk * 32 + 4);
            }
        }

        // park enc rows (f16, swizzled: byte ^= (row&7)<<4) for the context pass
        // (ci=0: encl fresh after A; ci>0: context reads drained at barrier E)
        {
            const int asw = (arow & 7) << 4;
            #pragma unroll
            for (int kk = 0; kk < 4; ++kk) {
                int byte = arow * 256 + (((kk * 64) + (g * 16)) ^ asw);
                *(half8*)(encl + byte) = afr[kk];
            }
        }

        floatx4 acc[8];
        #pragma unroll
        for (int ni = 0; ni < 8; ++ni) acc[ni] = (floatx4)0.0f;

        #pragma unroll
        for (int kk = 0; kk < 4; ++kk)
            #pragma unroll
            for (int ni = 0; ni < 8; ++ni)
                acc[ni] = __builtin_amdgcn_mfma_f32_16x16x32_f16(
                              afr[kk], bfr[(kk * 8 + ni) * 64 + l], acc[ni], 0, 0, 0);

        // epilogue: logit = sum_n tanh(score + bias[n]) * V[n]
        // C layout: col = ni*16 + (l&15), row = g*4 + j2   [m89-verified]
        float p[4];
        #pragma unroll
        for (int j2 = 0; j2 < 4; ++j2) {
            float q = 0.f;
            #pragma unroll
            for (int ni = 0; ni < 8; ++ni)
                q += tanh_fast(acc[ni][j2] + bs[ni]) * vv[ni];
            #pragma unroll
            for (int mk = 1; mk < 16; mk <<= 1)
                q += __shfl_xor(q, mk);
            p[j2] = q;
        }
        if ((l & 15) == 0) {
            floatx4 v4 = {p[0], p[1], p[2], p[3]};
            *(floatx4*)(&red[w * 16 + g * 4]) = v4;
            *(floatx4*)(out_w + (long)b * T_ + chunk * MBLK + w * 16 + g * 4) = v4;
        }
        __syncthreads();   // C: red[] + encl ready

        // exp weights, computed ONCE (bounded logits: |logit| <= sum|V| ~ 6.5)
        if (tid < 128) {
            float ew = __expf(red[tid]);
            ews[tid] = ew;
            float s = ew;
            #pragma unroll
            for (int mk = 1; mk < 64; mk <<= 1) s += __shfl_xor(s, mk);
            if ((tid & 63) == 0) sp[tid >> 6] = s;
        }
        __syncthreads();   // D: ews + sp ready
        if (tid == 0) s_part[b * NCHUNK + chunk] = sp[0] + sp[1];

        // context partial from LDS: 8 row-groups x 16 rows; 256 active threads
        if (tid < 256) {
            const int rg = tid >> 5, dg = tid & 31;
            floatx4 cc = (floatx4)0.0f;
            #pragma unroll
            for (int rr = 0; rr < 16; ++rr) {
                int r = rg * 16 + rr;
                float wgt = ews[r];
                half4 h = *(const half4*)(encl + (r * 256 + ((dg * 8) ^ ((r & 7) << 4))));
                #pragma unroll
                for (int i = 0; i < 4; ++i) cc[i] += wgt * (float)h[i];
            }
            *(floatx4*)(&c_red[rg][dg * 4]) = cc;
        }
        __syncthreads();   // E: c_red ready; encl reads drained (next park safe)
        if (tid < 128) {
            float s = 0.f;
            #pragma unroll
            for (int gg = 0; gg < 8; ++gg) s += c_red[gg][tid];
            c_part[((long)b * NCHUNK + chunk) * 128 + tid] = s;
        }
        // c_red WAR vs next chunk protected by next iteration's barriers C/D
    }
}

// K3 (merged tail, 512 blocks = 16 per batch): every block redundantly sums the
// 64 chunk exp-sums -> inv = 1/s_g; per-batch block 0 also emits the context
// vector; all blocks exponentiate+scale their 512-logit slice of out_w.
__global__ __launch_bounds__(256)
void tail_kernel(const float* __restrict__ s_part, const float* __restrict__ c_part,
                 float* __restrict__ ctx, float* __restrict__ out_w)
{
    __shared__ float stats[1];
    __shared__ float part[2][128];
    int bid = blockIdx.x, tid = threadIdx.x;
    int b = bid >> 4, j = bid & 15;

    if (tid < 64) {
        float s = s_part[b * 64 + tid];
        #pragma unroll
        for (int mk = 1; mk < 64; mk <<= 1) s += __shfl_xor(s, mk);
        if (tid == 0) stats[0] = __fdividef(1.0f, s);
    }
    __syncthreads();
    float inv = stats[0];

    if (j == 0) {   // context vector: sum 64 unnormalized partials, scale
        int d = tid & 127, h = tid >> 7;
        float acc = 0.f;
        #pragma unroll 4
        for (int ch = h * 32; ch < h * 32 + 32; ++ch)
            acc += c_part[((long)b * 64 + ch) * 128 + d];
        part[h][d] = acc;
        __syncthreads();
        if (tid < 128)
            ctx[b * 128 + tid] = (part[0][tid] + part[1][tid]) * inv;
    }

    // softmax weights: out_w[i] = exp(logit) * inv  (bounded logits, no max)
    float* ow = out_w + (long)b * T_ + j * 512;
    #pragma unroll
    for (int q = 0; q < 2; ++q) {
        int i = q * 256 + tid;
        ow[i] = __expf(ow[i]) * inv;
    }
}

extern "C" void kernel_launch(void* const* d_in, const int* in_sizes, int n_in,
                              void* d_out, int out_size, void* d_ws, size_t ws_size,
                              hipStream_t stream)
{
    const float* enc = (const float*)d_in[0];
    const float* dec = (const float*)d_in[1];
    const float* W1  = (const float*)d_in[2];
    const float* W2  = (const float*)d_in[3];
    const float* V   = (const float*)d_in[4];

    float* ctx  = (float*)d_out;          // [B, 128]
    float* outw = ctx + B_ * D_;          // [B, T]

    float* ws     = (float*)d_ws;
    float* bias   = ws;                   // 4096
    float* s_part = bias + 4096;          // 2048
    float* c_part = s_part + 2048;        // 2048*128 = 262144
    half8* W1frag = (half8*)(c_part + (long)B_ * NCHUNK * 128);  // 32 KB, 16B-aligned

    prep_kernel<<<24, 256, 0, stream>>>(W1, W1frag, dec, W2, bias);
    main_kernel<<<B_ * (NCHUNK / CPB), 512, 0, stream>>>(enc, W1frag, bias, V, outw, s_part, c_part);
    tail_kernel<<<B_ * 16, 256, 0, stream>>>(s_part, c_part, ctx, outw);
}